// Round 3
// baseline (387.734 us; speedup 1.0000x reference)
//
#include <hip/hip_runtime.h>

typedef __bf16 bf16x8 __attribute__((ext_vector_type(8)));
typedef float f32x4 __attribute__((ext_vector_type(4)));

#define MFMA(a, b, c) __builtin_amdgcn_mfma_f32_16x16x32_bf16((a), (b), (c), 0, 0, 0)

static __device__ __forceinline__ unsigned short f2b(float f) {
    // fp32 -> bf16, round-to-nearest-even
    unsigned int u = __builtin_bit_cast(unsigned int, f);
    unsigned int lsb = (u >> 16) & 1u;
    u += 0x7fffu + lsb;
    return (unsigned short)(u >> 16);
}

static __device__ __forceinline__ f32x4 zero4() {
    f32x4 z; z[0] = 0.f; z[1] = 0.f; z[2] = 0.f; z[3] = 0.f; return z;
}

// ---------------------------------------------------------------------------
// Prep: cast rel_pos -> bf16 [1024][64]; build ervT padded [64][1088] with
// ervT[dh][47 + r] = bf16(val_rel_pos[r][dh]), zeros elsewhere.
// pad=47: most negative column is 47 + db' + 0 = 16 >= 0 (db' = i0-j0-31 >= -31),
// and 47 + db' == 0 mod 16 keeps attention B-frag reads 16B-aligned.
// ---------------------------------------------------------------------------
__global__ __launch_bounds__(256) void prep_tables(
    const float* __restrict__ rel, const float* __restrict__ vrel,
    unsigned short* __restrict__ erb, unsigned short* __restrict__ ervT)
{
    int idx = blockIdx.x * 256 + threadIdx.x;
    if (idx < 1024 * 64) {
        erb[idx] = f2b(rel[idx]);
    }
    int j = idx - 1024 * 64;
    if (j >= 0 && j < 64 * 1088) {
        int dh = j / 1088, c = j % 1088;
        int r = c - 47;
        ervT[j] = (r >= 0 && r < 1024) ? f2b(vrel[r * 64 + dh]) : (unsigned short)0;
    }
}

// ---------------------------------------------------------------------------
// Projection GEMM: C[M=2048, N=1024] = X @ W^T + bias, output bf16.
// mode 0/1: out[((b*16+h)*1024 + s)*64 + dh]   (q / k row-major per head)
// mode 2 : out[((b*16+h)*64 + dh)*1024 + s]    (v transposed for PV B-frags)
// 128x128 tile, BK=32, 4 waves each owning a 64x64 quadrant.
// ---------------------------------------------------------------------------
__global__ __launch_bounds__(256) void proj_gemm(
    const float* __restrict__ X, const float* __restrict__ W,
    const float* __restrict__ bias, unsigned short* __restrict__ outp, int mode)
{
    __shared__ unsigned short As[128][48];  // stride 48 elems = 96B (16B-aligned rows)
    __shared__ unsigned short Bs[128][48];
    const int n0 = blockIdx.x * 128, m0 = blockIdx.y * 128;
    const int tid = threadIdx.x;
    const int lane = tid & 63, w = tid >> 6;
    const int wm = (w & 1) * 64, wn = (w >> 1) * 64;
    const int lr = lane & 15, lg = lane >> 4;

    f32x4 acc[4][4];
#pragma unroll
    for (int a = 0; a < 4; ++a)
#pragma unroll
        for (int bq = 0; bq < 4; ++bq) acc[a][bq] = zero4();

    for (int k0 = 0; k0 < 1024; k0 += 32) {
        __syncthreads();
#pragma unroll
        for (int it = 0; it < 4; ++it) {
            int g = tid + it * 256;            // 1024 groups of 4 elems
            int row = g >> 3, c4 = (g & 7) << 2;
            float4 xa = *(const float4*)(X + (size_t)(m0 + row) * 1024 + k0 + c4);
            ushort4 pa = make_ushort4(f2b(xa.x), f2b(xa.y), f2b(xa.z), f2b(xa.w));
            *(ushort4*)&As[row][c4] = pa;
            float4 xb = *(const float4*)(W + (size_t)(n0 + row) * 1024 + k0 + c4);
            ushort4 pb = make_ushort4(f2b(xb.x), f2b(xb.y), f2b(xb.z), f2b(xb.w));
            *(ushort4*)&Bs[row][c4] = pb;
        }
        __syncthreads();
        bf16x8 af[4], bfg[4];
#pragma unroll
        for (int t = 0; t < 4; ++t) {
            af[t]  = *(const bf16x8*)&As[wm + t * 16 + lr][lg * 8];
            bfg[t] = *(const bf16x8*)&Bs[wn + t * 16 + lr][lg * 8];
        }
#pragma unroll
        for (int mt = 0; mt < 4; ++mt)
#pragma unroll
            for (int nt = 0; nt < 4; ++nt)
                acc[mt][nt] = MFMA(af[mt], bfg[nt], acc[mt][nt]);
    }

#pragma unroll
    for (int mt = 0; mt < 4; ++mt)
#pragma unroll
        for (int nt = 0; nt < 4; ++nt)
#pragma unroll
            for (int r = 0; r < 4; ++r) {
                int m = m0 + wm + mt * 16 + lg * 4 + r;   // C row = (lane>>4)*4 + reg
                int n = n0 + wn + nt * 16 + lr;           // C col = lane&15
                float v = acc[mt][nt][r] + bias[n];
                int b = m >> 10, s = m & 1023, h = n >> 6, dh = n & 63;
                unsigned short bv = f2b(v);
                if (mode == 2)
                    outp[(((size_t)(b * 16 + h)) * 64 + dh) * 1024 + s] = bv;
                else
                    outp[(((size_t)(b * 16 + h)) * 1024 + s) * 64 + dh] = bv;
            }
}

// ---------------------------------------------------------------------------
// Fused causal attention with relative-position bias (scores and values).
// 1 wave per workgroup; wave owns 16 query rows; loops KV tiles of 32 cols.
// score[i,j] = (q_i.k_j + q_i.er[i-j]) / 8, j <= i ; online softmax;
// z_i = sum_j p[i,j] v_j + sum_j p[i,j] erv[i-j].
//
// Slot algebra: within a tile, t = row - jcol + 31 in [0,46]; distance
// d = i - j = db' + t with db' = i0 - j0 - 31. QE covers t in [0,47] via
// 3 MFMA tiles; PR (column-reversed P) covers t in [0,63] (two K=32 MFMAs;
// slots t>46 and unstored slots are permanently zero).
// ---------------------------------------------------------------------------
__global__ __launch_bounds__(64) void attn_kernel(
    const unsigned short* __restrict__ qb, const unsigned short* __restrict__ kb,
    const unsigned short* __restrict__ vtb, const unsigned short* __restrict__ erb,
    const unsigned short* __restrict__ ervT, float* __restrict__ out)
{
    const int qt = blockIdx.x, h = blockIdx.y, b = blockIdx.z;
    const int i0 = qt * 16, bh = b * 16 + h;
    const int lane = threadIdx.x;
    const int lr = lane & 15, lg = lane >> 4;

    __shared__ unsigned short p_lds[16][32];  // P tile, row-major (PV A-frag)
    __shared__ unsigned short prv[16][64];    // reversed P: prv[row][row+31-col] = P[row][col]
    for (int t = lane; t < 16 * 64; t += 64) ((unsigned short*)prv)[t] = 0;
    __syncthreads();

    // Q fragments: A-layout lane holds row (lane&15), k = (lane>>4)*8 + jj
    const unsigned short* qbase = qb + (((size_t)bh * 1024) + i0 + lr) * 64 + lg * 8;
    const bf16x8 qf0 = *(const bf16x8*)qbase;         // dh 0..31
    const bf16x8 qf1 = *(const bf16x8*)(qbase + 32);  // dh 32..63

    f32x4 oacc[4];
    float m_run[4], l_run[4];
#pragma unroll
    for (int r = 0; r < 4; ++r) { oacc[r] = zero4(); m_run[r] = -1e30f; l_run[r] = 0.f; }

    for (int j0 = 0; j0 <= i0 + 15; j0 += 32) {
        const int dbp = i0 - j0 - 31;  // distance of slot t=0

        // ---- QK^T: two 16x16 score tiles --------------------------------
        f32x4 sacc[2]; sacc[0] = zero4(); sacc[1] = zero4();
#pragma unroll
        for (int ct = 0; ct < 2; ++ct) {
            const unsigned short* kbase =
                kb + (((size_t)bh * 1024) + j0 + ct * 16 + lr) * 64 + lg * 8;
            bf16x8 kf0 = *(const bf16x8*)kbase;
            bf16x8 kf1 = *(const bf16x8*)(kbase + 32);
            sacc[ct] = MFMA(qf0, kf0, sacc[ct]);
            sacc[ct] = MFMA(qf1, kf1, sacc[ct]);
        }

        // ---- QE: q . er[dbp + t], t in [0,48) ---------------------------
        f32x4 qeacc[3];
#pragma unroll
        for (int st = 0; st < 3; ++st) {
            qeacc[st] = zero4();
            int dr = dbp + st * 16 + lr;
            dr = dr < 0 ? 0 : (dr > 1023 ? 1023 : dr);  // clamped rows feed masked slots only
            const unsigned short* ebase = erb + (size_t)dr * 64 + lg * 8;
            bf16x8 e0 = *(const bf16x8*)ebase;
            bf16x8 e1 = *(const bf16x8*)(ebase + 32);
            qeacc[st] = MFMA(qf0, e0, qeacc[st]);
            qeacc[st] = MFMA(qf1, e1, qeacc[st]);
        }

        // ---- bias gather (register shuffle), mask, scale ----------------
        float sc2[2][4];
#pragma unroll
        for (int ct = 0; ct < 2; ++ct)
#pragma unroll
            for (int r = 0; r < 4; ++r) {
                int row  = lg * 4 + r;
                int jcol = ct * 16 + lr;
                int t    = row - jcol + 31;                 // slot in [0,46]
                int srcl = (lane & 48) | (t & 15);          // same 16-lane group, same row
                float b0 = __shfl(qeacc[0][r], srcl, 64);
                float b1 = __shfl(qeacc[1][r], srcl, 64);
                float b2 = __shfl(qeacc[2][r], srcl, 64);
                int tb = t >> 4;
                float bias = tb == 0 ? b0 : (tb == 1 ? b1 : b2);
                float sc = (sacc[ct][r] + bias) * 0.125f;
                if (j0 + jcol > i0 + row) sc = -1e38f;      // causal mask
                sc2[ct][r] = sc;
            }

        // ---- online softmax --------------------------------------------
        float p2[2][4];
#pragma unroll
        for (int r = 0; r < 4; ++r) {
            float mx = fmaxf(sc2[0][r], sc2[1][r]);
#pragma unroll
            for (int off = 1; off < 16; off <<= 1)
                mx = fmaxf(mx, __shfl_xor(mx, off, 64));
            float mnew = fmaxf(m_run[r], mx);
            float scale = __expf(m_run[r] - mnew);
            float p0 = __expf(sc2[0][r] - mnew);
            float p1 = __expf(sc2[1][r] - mnew);
            float ps = p0 + p1;
#pragma unroll
            for (int off = 1; off < 16; off <<= 1)
                ps += __shfl_xor(ps, off, 64);
            l_run[r] = l_run[r] * scale + ps;
            m_run[r] = mnew;
#pragma unroll
            for (int dt = 0; dt < 4; ++dt) oacc[dt][r] *= scale;
            p2[0][r] = p0; p2[1][r] = p1;
        }

        // ---- write P (normal + column-reversed) to LDS ------------------
        __syncthreads();
#pragma unroll
        for (int ct = 0; ct < 2; ++ct)
#pragma unroll
            for (int r = 0; r < 4; ++r) {
                int row = lg * 4 + r, col = ct * 16 + lr;
                unsigned short pb = f2b(p2[ct][r]);
                p_lds[row][col] = pb;
                prv[row][row + 31 - col] = pb;   // slot t = row-col+31, in [row, row+31]
            }
        __syncthreads();

        // ---- PV + PR@Erv ------------------------------------------------
        bf16x8 pa   = *(const bf16x8*)&p_lds[lr][lg * 8];
        bf16x8 pra0 = *(const bf16x8*)&prv[lr][lg * 8];        // slots 0..31
        bf16x8 pra1 = *(const bf16x8*)&prv[lr][32 + lg * 8];   // slots 32..63
#pragma unroll
        for (int dt = 0; dt < 4; ++dt) {
            const unsigned short* vbase =
                vtb + ((size_t)bh * 64 + dt * 16 + lr) * 1024 + j0 + lg * 8;
            bf16x8 vf = *(const bf16x8*)vbase;
            oacc[dt] = MFMA(pa, vf, oacc[dt]);
            const unsigned short* rbase =
                ervT + (size_t)(dt * 16 + lr) * 1088 + 47 + dbp + lg * 8;
            bf16x8 rf0 = *(const bf16x8*)rbase;
            bf16x8 rf1 = *(const bf16x8*)(rbase + 32);
            oacc[dt] = MFMA(pra0, rf0, oacc[dt]);
            oacc[dt] = MFMA(pra1, rf1, oacc[dt]);
        }
    }

    // ---- epilogue: z = O / l, fp32 out [b, s, h*64+dh] ------------------
#pragma unroll
    for (int dt = 0; dt < 4; ++dt)
#pragma unroll
        for (int r = 0; r < 4; ++r) {
            int row = lg * 4 + r;
            int i = i0 + row;
            out[((size_t)(b * 1024 + i)) * 1024 + h * 64 + dt * 16 + lr] =
                oacc[dt][r] / l_run[r];
        }
}

// ---------------------------------------------------------------------------
extern "C" void kernel_launch(void* const* d_in, const int* in_sizes, int n_in,
                              void* d_out, int out_size, void* d_ws, size_t ws_size,
                              hipStream_t stream) {
    const float* query = (const float*)d_in[0];
    const float* key   = (const float*)d_in[1];
    const float* value = (const float*)d_in[2];
    const float* Wq    = (const float*)d_in[3];
    const float* bq    = (const float*)d_in[4];
    const float* Wk    = (const float*)d_in[5];
    const float* bk    = (const float*)d_in[6];
    const float* Wv    = (const float*)d_in[7];
    const float* bv    = (const float*)d_in[8];
    const float* rel   = (const float*)d_in[9];
    const float* vrel  = (const float*)d_in[10];
    float* out = (float*)d_out;

    char* w = (char*)d_ws;
    unsigned short* qb   = (unsigned short*)(w);              // 4 MiB  [B,H,S,Dh]
    unsigned short* kb   = (unsigned short*)(w + 4194304);    // 4 MiB  [B,H,S,Dh]
    unsigned short* vtb  = (unsigned short*)(w + 8388608);    // 4 MiB  [B,H,Dh,S]
    unsigned short* erb  = (unsigned short*)(w + 12582912);   // 128 KiB [1024,64]
    unsigned short* ervT = (unsigned short*)(w + 12713984);   // 136 KiB [64,1088]

    prep_tables<<<dim3(528), dim3(256), 0, stream>>>(rel, vrel, erb, ervT);
    dim3 pg(8, 16);
    proj_gemm<<<pg, dim3(256), 0, stream>>>(query, Wq, bq, qb, 0);
    proj_gemm<<<pg, dim3(256), 0, stream>>>(key,   Wk, bk, kb, 1);
    proj_gemm<<<pg, dim3(256), 0, stream>>>(value, Wv, bv, vtb, 2);
    attn_kernel<<<dim3(64, 16, 2), dim3(64), 0, stream>>>(qb, kb, vtb, erb, ervT, out);
}

// Round 5
// 273.605 us; speedup vs baseline: 1.4171x; 1.4171x over previous
//
#include <hip/hip_runtime.h>

typedef __bf16 bf16x8 __attribute__((ext_vector_type(8)));
typedef float f32x4 __attribute__((ext_vector_type(4)));

#define MFMA(a, b, c) __builtin_amdgcn_mfma_f32_16x16x32_bf16((a), (b), (c), 0, 0, 0)

static __device__ __forceinline__ unsigned short f2b(float f) {
    // fp32 -> bf16, round-to-nearest-even
    unsigned int u = __builtin_bit_cast(unsigned int, f);
    unsigned int lsb = (u >> 16) & 1u;
    u += 0x7fffu + lsb;
    return (unsigned short)(u >> 16);
}

static __device__ __forceinline__ f32x4 zero4() {
    f32x4 z; z[0] = 0.f; z[1] = 0.f; z[2] = 0.f; z[3] = 0.f; return z;
}

// ---------------------------------------------------------------------------
// Prep: cast rel_pos -> bf16 [1024][64]; build ervT padded [64][1088] with
// ervT[dh][47 + r] = bf16(val_rel_pos[r][dh]), zeros elsewhere.
// ---------------------------------------------------------------------------
__global__ __launch_bounds__(256) void prep_tables(
    const float* __restrict__ rel, const float* __restrict__ vrel,
    unsigned short* __restrict__ erb, unsigned short* __restrict__ ervT)
{
    int idx = blockIdx.x * 256 + threadIdx.x;
    if (idx < 1024 * 64) {
        erb[idx] = f2b(rel[idx]);
    }
    int j = idx - 1024 * 64;
    if (j >= 0 && j < 64 * 1088) {
        int dh = j / 1088, c = j % 1088;
        int r = c - 47;
        ervT[j] = (r >= 0 && r < 1024) ? f2b(vrel[r * 64 + dh]) : (unsigned short)0;
    }
}

// ---------------------------------------------------------------------------
// Fused projection GEMMs: one dispatch, blockIdx.z selects {q,k,v}.
// C[M=2048, N=1024] = X @ W^T + bias, output bf16.
// z 0/1: out[((b*16+h)*1024 + s)*64 + dh]   (q/k row-major per head)
// z 2  : out[((b*16+h)*64 + dh)*1024 + s]   (v transposed for PV B-frags)
// 128x64 tile, BK=32, 4 waves each owning a 64x32 quadrant -> 768 blocks
// (3/CU) instead of 3x128 blocks (0.5/CU): latency-bound fix.
// ---------------------------------------------------------------------------
__global__ __launch_bounds__(256) void proj_gemm_all(
    const float* __restrict__ Xq, const float* __restrict__ Xk, const float* __restrict__ Xv,
    const float* __restrict__ Wqp, const float* __restrict__ Wkp, const float* __restrict__ Wvp,
    const float* __restrict__ bqp, const float* __restrict__ bkp, const float* __restrict__ bvp,
    unsigned short* __restrict__ oq, unsigned short* __restrict__ ok, unsigned short* __restrict__ ov)
{
    const int z = blockIdx.z;
    const float* X    = z == 0 ? Xq  : z == 1 ? Xk  : Xv;
    const float* W    = z == 0 ? Wqp : z == 1 ? Wkp : Wvp;
    const float* bias = z == 0 ? bqp : z == 1 ? bkp : bvp;
    unsigned short* outp = z == 0 ? oq : z == 1 ? ok : ov;

    __shared__ unsigned short As[128][48];  // 96B row stride (16B-aligned)
    __shared__ unsigned short Bs[64][48];
    const int n0 = blockIdx.x * 64, m0 = blockIdx.y * 128;
    const int tid = threadIdx.x;
    const int lane = tid & 63, w = tid >> 6;
    const int wm = (w & 1) * 64, wn = (w >> 1) * 32;
    const int lr = lane & 15, lg = lane >> 4;

    f32x4 acc[4][2];
#pragma unroll
    for (int a = 0; a < 4; ++a)
#pragma unroll
        for (int bq = 0; bq < 2; ++bq) acc[a][bq] = zero4();

    for (int k0 = 0; k0 < 1024; k0 += 32) {
        __syncthreads();
#pragma unroll
        for (int it = 0; it < 2; ++it) {   // A tile: 128x32 = 4096 elems
            int g = tid + it * 256;        // 512 groups of 8 elems
            int row = g >> 2, c8 = (g & 3) << 3;
            float4 xa = *(const float4*)(X + (size_t)(m0 + row) * 1024 + k0 + c8);
            float4 xb = *(const float4*)(X + (size_t)(m0 + row) * 1024 + k0 + c8 + 4);
            *(ushort4*)&As[row][c8]     = make_ushort4(f2b(xa.x), f2b(xa.y), f2b(xa.z), f2b(xa.w));
            *(ushort4*)&As[row][c8 + 4] = make_ushort4(f2b(xb.x), f2b(xb.y), f2b(xb.z), f2b(xb.w));
        }
        {                                   // B tile: 64x32 = 2048 elems
            int g = tid;                    // 256 groups of 8
            int row = g >> 2, c8 = (g & 3) << 3;
            float4 xa = *(const float4*)(W + (size_t)(n0 + row) * 1024 + k0 + c8);
            float4 xb = *(const float4*)(W + (size_t)(n0 + row) * 1024 + k0 + c8 + 4);
            *(ushort4*)&Bs[row][c8]     = make_ushort4(f2b(xa.x), f2b(xa.y), f2b(xa.z), f2b(xa.w));
            *(ushort4*)&Bs[row][c8 + 4] = make_ushort4(f2b(xb.x), f2b(xb.y), f2b(xb.z), f2b(xb.w));
        }
        __syncthreads();
        bf16x8 af[4], bfg[2];
#pragma unroll
        for (int t = 0; t < 4; ++t) af[t] = *(const bf16x8*)&As[wm + t * 16 + lr][lg * 8];
#pragma unroll
        for (int t = 0; t < 2; ++t) bfg[t] = *(const bf16x8*)&Bs[wn + t * 16 + lr][lg * 8];
#pragma unroll
        for (int mt = 0; mt < 4; ++mt)
#pragma unroll
            for (int nt = 0; nt < 2; ++nt)
                acc[mt][nt] = MFMA(af[mt], bfg[nt], acc[mt][nt]);
    }

#pragma unroll
    for (int mt = 0; mt < 4; ++mt)
#pragma unroll
        for (int nt = 0; nt < 2; ++nt)
#pragma unroll
            for (int r = 0; r < 4; ++r) {
                int m = m0 + wm + mt * 16 + lg * 4 + r;   // C row = (lane>>4)*4 + reg
                int n = n0 + wn + nt * 16 + lr;           // C col = lane&15
                float v = acc[mt][nt][r] + bias[n];
                int b = m >> 10, s = m & 1023, h = n >> 6, dh = n & 63;
                unsigned short bv = f2b(v);
                if (z == 2)
                    outp[(((size_t)(b * 16 + h)) * 64 + dh) * 1024 + s] = bv;
                else
                    outp[(((size_t)(b * 16 + h)) * 1024 + s) * 64 + dh] = bv;
            }
}

// ---------------------------------------------------------------------------
// Fused causal attention with relative-position bias (scores and values).
// 4 waves per block; all share one 16-row q-tile and split the KV tiles
// (wave w takes tiles w, w+4, ...), each with private online-softmax state
// and a private P/PR LDS slice (no in-loop barriers: same-wave DS ops are
// in-order; sched_barrier pins compile-time order). Partials merged via LDS.
//
// Slot algebra: t = row - jcol + 31 in [0,46]; distance d = dbp + t with
// dbp = i0 - j0 - 31. QE covers t in [0,48) (3 MFMA tiles); PR covers
// t in [0,64) (two K=32 MFMAs; slots t>46 / unstored stay zero).
// ---------------------------------------------------------------------------
__global__ __launch_bounds__(256) void attn_kernel(
    const unsigned short* __restrict__ qb, const unsigned short* __restrict__ kb,
    const unsigned short* __restrict__ vtb, const unsigned short* __restrict__ erb,
    const unsigned short* __restrict__ ervT, float* __restrict__ out)
{
    const int qt = blockIdx.x, h = blockIdx.y, b = blockIdx.z;
    const int i0 = qt * 16, bh = b * 16 + h;
    const int tid = threadIdx.x;
    const int lane = tid & 63, w = tid >> 6;
    const int lr = lane & 15, lg = lane >> 4;

    // Loop phase: p_lds[4][16][32] (4KB) + prv[4][16][64] (8KB), per-wave slices.
    // Combine phase (after barrier, unioned): pO[4][16][64] f32 (16KB) + pm/pl.
    __shared__ __align__(16) char smem[16896];
    unsigned short* p_lds = (unsigned short*)smem + w * (16 * 32);
    unsigned short* prv   = (unsigned short*)(smem + 4096) + w * (16 * 64);
    float* pO = (float*)smem;             // [4][16][64]
    float* pm = (float*)(smem + 16384);   // [4][16]
    float* pl = pm + 64;                  // [4][16]

    // zero own prv slice (wave-local; same-wave DS ordering suffices)
    for (int t = lane; t < 16 * 64; t += 64) prv[t] = 0;

    // Q fragments: A-layout lane holds row (lane&15), k = (lane>>4)*8 + jj
    const unsigned short* qbase = qb + (((size_t)bh * 1024) + i0 + lr) * 64 + lg * 8;
    const bf16x8 qf0 = *(const bf16x8*)qbase;         // dh 0..31
    const bf16x8 qf1 = *(const bf16x8*)(qbase + 32);  // dh 32..63

    f32x4 oacc[4];
    float m_run[4], l_run[4];
#pragma unroll
    for (int r = 0; r < 4; ++r) { oacc[r] = zero4(); m_run[r] = -1e30f; l_run[r] = 0.f; }

    const int ntiles = (i0 + 15) / 32 + 1;
    for (int ti = w; ti < ntiles; ti += 4) {
        const int j0 = ti * 32;
        const int dbp = i0 - j0 - 31;  // distance of slot t=0

        // ---- QK^T: two 16x16 score tiles --------------------------------
        f32x4 sacc[2]; sacc[0] = zero4(); sacc[1] = zero4();
#pragma unroll
        for (int ct = 0; ct < 2; ++ct) {
            const unsigned short* kbase =
                kb + (((size_t)bh * 1024) + j0 + ct * 16 + lr) * 64 + lg * 8;
            bf16x8 kf0 = *(const bf16x8*)kbase;
            bf16x8 kf1 = *(const bf16x8*)(kbase + 32);
            sacc[ct] = MFMA(qf0, kf0, sacc[ct]);
            sacc[ct] = MFMA(qf1, kf1, sacc[ct]);
        }

        // ---- QE: q . er[dbp + t], t in [0,48) ---------------------------
        f32x4 qeacc[3];
#pragma unroll
        for (int st = 0; st < 3; ++st) {
            qeacc[st] = zero4();
            int dr = dbp + st * 16 + lr;
            dr = dr < 0 ? 0 : (dr > 1023 ? 1023 : dr);  // clamped rows feed masked slots only
            const unsigned short* ebase = erb + (size_t)dr * 64 + lg * 8;
            bf16x8 e0 = *(const bf16x8*)ebase;
            bf16x8 e1 = *(const bf16x8*)(ebase + 32);
            qeacc[st] = MFMA(qf0, e0, qeacc[st]);
            qeacc[st] = MFMA(qf1, e1, qeacc[st]);
        }

        // ---- bias gather (register shuffle), mask, scale ----------------
        float sc2[2][4];
#pragma unroll
        for (int ct = 0; ct < 2; ++ct)
#pragma unroll
            for (int r = 0; r < 4; ++r) {
                int row  = lg * 4 + r;
                int jcol = ct * 16 + lr;
                int t    = row - jcol + 31;                 // slot in [0,46]
                int srcl = (lane & 48) | (t & 15);          // same 16-lane group
                float b0 = __shfl(qeacc[0][r], srcl, 64);
                float b1 = __shfl(qeacc[1][r], srcl, 64);
                float b2 = __shfl(qeacc[2][r], srcl, 64);
                int tb = t >> 4;
                float bias = tb == 0 ? b0 : (tb == 1 ? b1 : b2);
                float sc = (sacc[ct][r] + bias) * 0.125f;
                if (j0 + jcol > i0 + row) sc = -1e38f;      // causal mask
                sc2[ct][r] = sc;
            }

        // ---- online softmax (wave-private state) ------------------------
        float p2[2][4];
#pragma unroll
        for (int r = 0; r < 4; ++r) {
            float mx = fmaxf(sc2[0][r], sc2[1][r]);
#pragma unroll
            for (int off = 1; off < 16; off <<= 1)
                mx = fmaxf(mx, __shfl_xor(mx, off, 64));
            float mnew = fmaxf(m_run[r], mx);
            float scale = __expf(m_run[r] - mnew);
            float p0 = __expf(sc2[0][r] - mnew);
            float p1 = __expf(sc2[1][r] - mnew);
            float ps = p0 + p1;
#pragma unroll
            for (int off = 1; off < 16; off <<= 1)
                ps += __shfl_xor(ps, off, 64);
            l_run[r] = l_run[r] * scale + ps;
            m_run[r] = mnew;
#pragma unroll
            for (int dt = 0; dt < 4; ++dt) oacc[dt][r] *= scale;
            p2[0][r] = p0; p2[1][r] = p1;
        }

        // ---- write P (normal + column-reversed) to own LDS slice --------
#pragma unroll
        for (int ct = 0; ct < 2; ++ct)
#pragma unroll
            for (int r = 0; r < 4; ++r) {
                int row = lg * 4 + r, col = ct * 16 + lr;
                unsigned short pb = f2b(p2[ct][r]);
                p_lds[row * 32 + col] = pb;
                prv[row * 64 + (row + 31 - col)] = pb;  // slot t in [row, row+31]
            }
        __builtin_amdgcn_sched_barrier(0);  // keep DS writes before the reads below

        // ---- PV + PR@Erv ------------------------------------------------
        bf16x8 pa   = *(const bf16x8*)&p_lds[lr * 32 + lg * 8];
        bf16x8 pra0 = *(const bf16x8*)&prv[lr * 64 + lg * 8];        // slots 0..31
        bf16x8 pra1 = *(const bf16x8*)&prv[lr * 64 + 32 + lg * 8];   // slots 32..63
#pragma unroll
        for (int dt = 0; dt < 4; ++dt) {
            const unsigned short* vbase =
                vtb + ((size_t)bh * 64 + dt * 16 + lr) * 1024 + j0 + lg * 8;
            bf16x8 vf = *(const bf16x8*)vbase;
            oacc[dt] = MFMA(pa, vf, oacc[dt]);
            const unsigned short* rbase =
                ervT + (size_t)(dt * 16 + lr) * 1088 + 47 + dbp + lg * 8;
            bf16x8 rf0 = *(const bf16x8*)rbase;
            bf16x8 rf1 = *(const bf16x8*)(rbase + 32);
            oacc[dt] = MFMA(pra0, rf0, oacc[dt]);
            oacc[dt] = MFMA(pra1, rf1, oacc[dt]);
        }
    }

    // ---- merge the 4 wave-partials via LDS ------------------------------
    __syncthreads();  // all loop-phase LDS reads done before pO overwrites
#pragma unroll
    for (int dt = 0; dt < 4; ++dt)
#pragma unroll
        for (int r = 0; r < 4; ++r)
            pO[w * 1024 + (lg * 4 + r) * 64 + dt * 16 + lr] = oacc[dt][r];
    if (lr == 0)
#pragma unroll
        for (int r = 0; r < 4; ++r) {
            pm[w * 16 + lg * 4 + r] = m_run[r];
            pl[w * 16 + lg * 4 + r] = l_run[r];
        }
    __syncthreads();

    // 16x64 outputs over 256 threads (4 cells each)
#pragma unroll
    for (int k = 0; k < 4; ++k) {
        int c = k * 256 + tid;
        int row = c >> 6, dh = c & 63;
        float m0 = pm[row], m1 = pm[16 + row], m2 = pm[32 + row], m3 = pm[48 + row];
        float mf = fmaxf(fmaxf(m0, m1), fmaxf(m2, m3));
        float e0 = __expf(m0 - mf), e1 = __expf(m1 - mf);
        float e2 = __expf(m2 - mf), e3 = __expf(m3 - mf);
        float den = e0 * pl[row] + e1 * pl[16 + row] + e2 * pl[32 + row] + e3 * pl[48 + row];
        float num = e0 * pO[row * 64 + dh]        + e1 * pO[1024 + row * 64 + dh]
                  + e2 * pO[2048 + row * 64 + dh] + e3 * pO[3072 + row * 64 + dh];
        out[((size_t)(b * 1024 + i0 + row)) * 1024 + h * 64 + dh] = num / den;
    }
}

// ---------------------------------------------------------------------------
extern "C" void kernel_launch(void* const* d_in, const int* in_sizes, int n_in,
                              void* d_out, int out_size, void* d_ws, size_t ws_size,
                              hipStream_t stream) {
    const float* query = (const float*)d_in[0];
    const float* key   = (const float*)d_in[1];
    const float* value = (const float*)d_in[2];
    const float* Wq    = (const float*)d_in[3];
    const float* bq    = (const float*)d_in[4];
    const float* Wk    = (const float*)d_in[5];
    const float* bk    = (const float*)d_in[6];
    const float* Wv    = (const float*)d_in[7];
    const float* bv    = (const float*)d_in[8];
    const float* rel   = (const float*)d_in[9];
    const float* vrel  = (const float*)d_in[10];
    float* out = (float*)d_out;

    char* w = (char*)d_ws;
    unsigned short* qb   = (unsigned short*)(w);              // 4 MiB  [B,H,S,Dh]
    unsigned short* kb   = (unsigned short*)(w + 4194304);    // 4 MiB  [B,H,S,Dh]
    unsigned short* vtb  = (unsigned short*)(w + 8388608);    // 4 MiB  [B,H,Dh,S]
    unsigned short* erb  = (unsigned short*)(w + 12582912);   // 128 KiB [1024,64]
    unsigned short* ervT = (unsigned short*)(w + 12713984);   // 136 KiB [64,1088]

    prep_tables<<<dim3(528), dim3(256), 0, stream>>>(rel, vrel, erb, ervT);
    proj_gemm_all<<<dim3(16, 16, 3), dim3(256), 0, stream>>>(
        query, key, value, Wq, Wk, Wv, bq, bk, bv, qb, kb, vtb);
    attn_kernel<<<dim3(64, 16, 2), dim3(256), 0, stream>>>(qb, kb, vtb, erb, ervT, out);
}

// Round 7
// 260.856 us; speedup vs baseline: 1.4864x; 1.0489x over previous
//
#include <hip/hip_runtime.h>

typedef __bf16 bf16x8 __attribute__((ext_vector_type(8)));
typedef float f32x4 __attribute__((ext_vector_type(4)));

#define MFMA(a, b, c) __builtin_amdgcn_mfma_f32_16x16x32_bf16((a), (b), (c), 0, 0, 0)

// DPP cross-lane (16-lane row reduce): quad_perm xor1=0xB1, xor2=0x4E, row_ror:4=0x124, row_ror:8=0x128
#define DPPF(x, ctrl) __builtin_bit_cast(float, __builtin_amdgcn_mov_dpp(__builtin_bit_cast(int, (x)), (ctrl), 0xF, 0xF, true))

static __device__ __forceinline__ float rowmax16(float v) {
    v = fmaxf(v, DPPF(v, 0xB1));
    v = fmaxf(v, DPPF(v, 0x4E));
    v = fmaxf(v, DPPF(v, 0x124));
    v = fmaxf(v, DPPF(v, 0x128));
    return v;
}
static __device__ __forceinline__ float rowsum16(float v) {
    v += DPPF(v, 0xB1);
    v += DPPF(v, 0x4E);
    v += DPPF(v, 0x124);
    v += DPPF(v, 0x128);
    return v;
}

static __device__ __forceinline__ unsigned short f2b(float f) {
    // fp32 -> bf16, round-to-nearest-even
    unsigned int u = __builtin_bit_cast(unsigned int, f);
    unsigned int lsb = (u >> 16) & 1u;
    u += 0x7fffu + lsb;
    return (unsigned short)(u >> 16);
}

static __device__ __forceinline__ f32x4 zero4() {
    f32x4 z; z[0] = 0.f; z[1] = 0.f; z[2] = 0.f; z[3] = 0.f; return z;
}

// ---------------------------------------------------------------------------
// Prep: cast rel_pos -> bf16 [1024][64]; build ervT padded [64][1088] with
// ervT[dh][47 + r] = bf16(val_rel_pos[r][dh]), zeros elsewhere.
// ---------------------------------------------------------------------------
__global__ __launch_bounds__(256) void prep_tables(
    const float* __restrict__ rel, const float* __restrict__ vrel,
    unsigned short* __restrict__ erb, unsigned short* __restrict__ ervT)
{
    int idx = blockIdx.x * 256 + threadIdx.x;
    if (idx < 1024 * 64) {
        erb[idx] = f2b(rel[idx]);
    }
    int j = idx - 1024 * 64;
    if (j >= 0 && j < 64 * 1088) {
        int dh = j / 1088, c = j % 1088;
        int r = c - 47;
        ervT[j] = (r >= 0 && r < 1024) ? f2b(vrel[r * 64 + dh]) : (unsigned short)0;
    }
}

// ---------------------------------------------------------------------------
// Fused projection GEMMs, one dispatch. blockIdx.z selects {q,k,v}.
// C[M=2048, N=1024] = X @ W^T + bias, bf16 out.
// 128x128 tile, BK=32, 4 waves x 64x64 quadrant.
// grid.x = M-tile so all 8 N-blocks sharing an X-panel have the same
// linear%8 -> same XCD -> X panel cached once per XCD (HBM re-read fix).
// ---------------------------------------------------------------------------
__global__ __launch_bounds__(256, 4) void proj_gemm_all(
    const float* __restrict__ Xq, const float* __restrict__ Xk, const float* __restrict__ Xv,
    const float* __restrict__ Wqp, const float* __restrict__ Wkp, const float* __restrict__ Wvp,
    const float* __restrict__ bqp, const float* __restrict__ bkp, const float* __restrict__ bvp,
    unsigned short* __restrict__ oq, unsigned short* __restrict__ ok, unsigned short* __restrict__ ov)
{
    const int z = blockIdx.z;
    const float* X    = z == 0 ? Xq  : z == 1 ? Xk  : Xv;
    const float* W    = z == 0 ? Wqp : z == 1 ? Wkp : Wvp;
    const float* bias = z == 0 ? bqp : z == 1 ? bkp : bvp;
    unsigned short* outp = z == 0 ? oq : z == 1 ? ok : ov;

    __shared__ unsigned short As[128][56];  // 112B stride: 16B-aligned rows, 2-way banks
    __shared__ unsigned short Bs[128][56];
    const int m0 = blockIdx.x * 128, n0 = blockIdx.y * 128;
    const int tid = threadIdx.x;
    const int lane = tid & 63, w = tid >> 6;
    const int wm = (w & 1) * 64, wn = (w >> 1) * 64;
    const int lr = lane & 15, lg = lane >> 4;

    f32x4 acc[4][4];
#pragma unroll
    for (int a = 0; a < 4; ++a)
#pragma unroll
        for (int bq = 0; bq < 4; ++bq) acc[a][bq] = zero4();

    for (int k0 = 0; k0 < 1024; k0 += 32) {
        __syncthreads();
#pragma unroll
        for (int it = 0; it < 2; ++it) {   // A: 128x32 fp32 -> bf16
            int g = tid + it * 256;        // 512 groups of 8
            int row = g >> 2, c8 = (g & 3) << 3;
            float4 xa = *(const float4*)(X + (size_t)(m0 + row) * 1024 + k0 + c8);
            float4 xb = *(const float4*)(X + (size_t)(m0 + row) * 1024 + k0 + c8 + 4);
            *(ushort4*)&As[row][c8]     = make_ushort4(f2b(xa.x), f2b(xa.y), f2b(xa.z), f2b(xa.w));
            *(ushort4*)&As[row][c8 + 4] = make_ushort4(f2b(xb.x), f2b(xb.y), f2b(xb.z), f2b(xb.w));
        }
#pragma unroll
        for (int it = 0; it < 2; ++it) {   // B: 128x32
            int g = tid + it * 256;
            int row = g >> 2, c8 = (g & 3) << 3;
            float4 xa = *(const float4*)(W + (size_t)(n0 + row) * 1024 + k0 + c8);
            float4 xb = *(const float4*)(W + (size_t)(n0 + row) * 1024 + k0 + c8 + 4);
            *(ushort4*)&Bs[row][c8]     = make_ushort4(f2b(xa.x), f2b(xa.y), f2b(xa.z), f2b(xa.w));
            *(ushort4*)&Bs[row][c8 + 4] = make_ushort4(f2b(xb.x), f2b(xb.y), f2b(xb.z), f2b(xb.w));
        }
        __syncthreads();
        bf16x8 af[4], bfg[4];
#pragma unroll
        for (int t = 0; t < 4; ++t) {
            af[t]  = *(const bf16x8*)&As[wm + t * 16 + lr][lg * 8];
            bfg[t] = *(const bf16x8*)&Bs[wn + t * 16 + lr][lg * 8];
        }
#pragma unroll
        for (int mt = 0; mt < 4; ++mt)
#pragma unroll
            for (int nt = 0; nt < 4; ++nt)
                acc[mt][nt] = MFMA(af[mt], bfg[nt], acc[mt][nt]);
    }

#pragma unroll
    for (int mt = 0; mt < 4; ++mt)
#pragma unroll
        for (int nt = 0; nt < 4; ++nt)
#pragma unroll
            for (int r = 0; r < 4; ++r) {
                int m = m0 + wm + mt * 16 + lg * 4 + r;   // C row = (lane>>4)*4 + reg
                int n = n0 + wn + nt * 16 + lr;           // C col = lane&15
                float v = acc[mt][nt][r] + bias[n];
                int b = m >> 10, s = m & 1023, h = n >> 6, dh = n & 63;
                unsigned short bv = f2b(v);
                if (z == 2)
                    outp[(((size_t)(b * 16 + h)) * 64 + dh) * 1024 + s] = bv;
                else
                    outp[(((size_t)(b * 16 + h)) * 1024 + s) * 64 + dh] = bv;
            }
}

// ---------------------------------------------------------------------------
// Fused causal attention with relative-position bias (scores and values).
// Each block handles paired q-tiles (qt, 63-qt) -> uniform 33 KV-tiles/block.
// 4 waves split KV tiles; wave-private online-softmax state + private LDS
// slices (no in-loop barriers). Bias gather via per-wave LDS scatter/read;
// softmax reduce via DPP (no DS cross-lane ops). Partials merged via LDS.
//
// Slot algebra: t = row - jcol + 31 in [0,46]; d = dbp + t, dbp = i0-j0-31.
// QE covers t in [0,48) (3 MFMA tiles); PR covers t in [0,64) (2 K=32 MFMAs).
// ---------------------------------------------------------------------------
__global__ __launch_bounds__(256, 4) void attn_kernel(
    const unsigned short* __restrict__ qb, const unsigned short* __restrict__ kb,
    const unsigned short* __restrict__ vtb, const unsigned short* __restrict__ erb,
    const unsigned short* __restrict__ ervT, float* __restrict__ out)
{
    const int bx = blockIdx.x, h = blockIdx.y, b = blockIdx.z;
    const int bh = b * 16 + h;
    const int tid = threadIdx.x;
    const int lane = tid & 63, w = tid >> 6;
    const int lr = lane & 15, lg = lane >> 4;

    // Layout: [0,12800) qe (4 x [16][50] f32) | [12800,16896) p (4 x [16][32] u16)
    //         [16896,17408) pm/pl | [17408,25600) prv (4 x [16][64] u16)
    // Combine-phase pO = [0,16384) f32 (after barrier; never touches pm/pl/prv).
    __shared__ __align__(16) char smem[25600];
    float* qe_w = (float*)(smem + w * 3200);                          // [16][50]
    unsigned short* p_w   = (unsigned short*)(smem + 12800 + w * 1024);  // [16][32]
    unsigned short* prv_w = (unsigned short*)(smem + 17408 + w * 2048);  // [16][64]
    float* pO = (float*)smem;              // [4][16][64]
    float* pm = (float*)(smem + 16896);    // [4][16]
    float* pl = pm + 64;                   // [4][16]

    // zero own prv slice once; unwritten slots stay zero forever
    for (int t = lane; t < 16 * 64; t += 64) prv_w[t] = 0;

    for (int seg = 0; seg < 2; ++seg) {
        const int qt = seg == 0 ? bx : 63 - bx;
        const int i0 = qt * 16;

        // Q fragments: A-layout lane holds row (lane&15), k = (lane>>4)*8 + jj
        const unsigned short* qbase = qb + (((size_t)bh * 1024) + i0 + lr) * 64 + lg * 8;
        const bf16x8 qf0 = *(const bf16x8*)qbase;         // dh 0..31
        const bf16x8 qf1 = *(const bf16x8*)(qbase + 32);  // dh 32..63

        f32x4 oacc[4];
        float m_run[4], l_run[4];
#pragma unroll
        for (int r = 0; r < 4; ++r) { oacc[r] = zero4(); m_run[r] = -1e30f; l_run[r] = 0.f; }

        const int ntiles = qt / 2 + 1;
        for (int ti = w; ti < ntiles; ti += 4) {
            const int j0 = ti * 32;
            const int dbp = i0 - j0 - 31;  // distance of slot t=0

            // ---- QK^T: two 16x16 score tiles ----------------------------
            f32x4 sacc[2]; sacc[0] = zero4(); sacc[1] = zero4();
#pragma unroll
            for (int ct = 0; ct < 2; ++ct) {
                const unsigned short* kbase =
                    kb + (((size_t)bh * 1024) + j0 + ct * 16 + lr) * 64 + lg * 8;
                bf16x8 kf0 = *(const bf16x8*)kbase;
                bf16x8 kf1 = *(const bf16x8*)(kbase + 32);
                sacc[ct] = MFMA(qf0, kf0, sacc[ct]);
                sacc[ct] = MFMA(qf1, kf1, sacc[ct]);
            }

            // ---- QE: q . er[dbp + t], t in [0,48) -----------------------
            f32x4 qeacc[3];
#pragma unroll
            for (int st = 0; st < 3; ++st) {
                qeacc[st] = zero4();
                int dr = dbp + st * 16 + lr;
                dr = dr < 0 ? 0 : (dr > 1023 ? 1023 : dr);  // clamped rows feed masked slots only
                const unsigned short* ebase = erb + (size_t)dr * 64 + lg * 8;
                bf16x8 e0 = *(const bf16x8*)ebase;
                bf16x8 e1 = *(const bf16x8*)(ebase + 32);
                qeacc[st] = MFMA(qf0, e0, qeacc[st]);
                qeacc[st] = MFMA(qf1, e1, qeacc[st]);
            }

            // ---- scatter qe bias to own LDS (row-major, [16][50] f32) ---
#pragma unroll
            for (int st = 0; st < 3; ++st)
#pragma unroll
                for (int r = 0; r < 4; ++r)
                    qe_w[(lg * 4 + r) * 50 + st * 16 + lr] = qeacc[st][r];

            // ---- V loads hoisted (latency hides under softmax) ----------
            bf16x8 vf[4];
#pragma unroll
            for (int dt = 0; dt < 4; ++dt)
                vf[dt] = *(const bf16x8*)(vtb + ((size_t)bh * 64 + dt * 16 + lr) * 1024 + j0 + lg * 8);

            // ---- gather bias, mask, scale -------------------------------
            float sc2[2][4];
#pragma unroll
            for (int ct = 0; ct < 2; ++ct)
#pragma unroll
                for (int r = 0; r < 4; ++r) {
                    int row  = lg * 4 + r;
                    int jcol = ct * 16 + lr;
                    int t    = row - jcol + 31;             // slot in [0,46]
                    float qv = qe_w[row * 50 + t];
                    float sc = (sacc[ct][r] + qv) * 0.125f;
                    if (j0 + jcol > i0 + row) sc = -1e38f;  // causal mask
                    sc2[ct][r] = sc;
                }

            // ---- online softmax: DPP 16-lane row reduce -----------------
            float p2[2][4];
#pragma unroll
            for (int r = 0; r < 4; ++r) {
                float mx = rowmax16(fmaxf(sc2[0][r], sc2[1][r]));
                float mnew = fmaxf(m_run[r], mx);
                float scale = __expf(m_run[r] - mnew);
                float p0 = __expf(sc2[0][r] - mnew);
                float p1 = __expf(sc2[1][r] - mnew);
                float ps = rowsum16(p0 + p1);
                l_run[r] = l_run[r] * scale + ps;
                m_run[r] = mnew;
#pragma unroll
                for (int dt = 0; dt < 4; ++dt) oacc[dt][r] *= scale;
                p2[0][r] = p0; p2[1][r] = p1;
            }

            // ---- write P (normal + column-reversed) to own LDS slices ---
#pragma unroll
            for (int ct = 0; ct < 2; ++ct)
#pragma unroll
                for (int r = 0; r < 4; ++r) {
                    int row = lg * 4 + r, col = ct * 16 + lr;
                    unsigned short pb = f2b(p2[ct][r]);
                    p_w[row * 32 + col] = pb;
                    prv_w[row * 64 + (row + 31 - col)] = pb;  // slot t in [row, row+31]
                }

            // ---- PV + PR@Erv --------------------------------------------
            bf16x8 pa   = *(const bf16x8*)&p_w[lr * 32 + lg * 8];
            bf16x8 pra0 = *(const bf16x8*)&prv_w[lr * 64 + lg * 8];       // slots 0..31
            bf16x8 pra1 = *(const bf16x8*)&prv_w[lr * 64 + 32 + lg * 8];  // slots 32..63
#pragma unroll
            for (int dt = 0; dt < 4; ++dt) {
                oacc[dt] = MFMA(pa, vf[dt], oacc[dt]);
                const unsigned short* rbase =
                    ervT + (size_t)(dt * 16 + lr) * 1088 + 47 + dbp + lg * 8;
                bf16x8 rf0 = *(const bf16x8*)rbase;
                bf16x8 rf1 = *(const bf16x8*)(rbase + 32);
                oacc[dt] = MFMA(pra0, rf0, oacc[dt]);
                oacc[dt] = MFMA(pra1, rf1, oacc[dt]);
            }
        }

        // ---- merge the 4 wave-partials via LDS --------------------------
        __syncthreads();  // loop-phase LDS reads done before pO overwrites
#pragma unroll
        for (int dt = 0; dt < 4; ++dt)
#pragma unroll
            for (int r = 0; r < 4; ++r)
                pO[w * 1024 + (lg * 4 + r) * 64 + dt * 16 + lr] = oacc[dt][r];
        if (lr == 0)
#pragma unroll
            for (int r = 0; r < 4; ++r) {
                pm[w * 16 + lg * 4 + r] = m_run[r];
                pl[w * 16 + lg * 4 + r] = l_run[r];
            }
        __syncthreads();

        // 16x64 outputs over 256 threads (4 cells each)
#pragma unroll
        for (int k = 0; k < 4; ++k) {
            int c = k * 256 + tid;
            int row = c >> 6, dh = c & 63;
            float m0 = pm[row], m1 = pm[16 + row], m2 = pm[32 + row], m3 = pm[48 + row];
            float mf = fmaxf(fmaxf(m0, m1), fmaxf(m2, m3));
            float e0 = __expf(m0 - mf), e1 = __expf(m1 - mf);
            float e2 = __expf(m2 - mf), e3 = __expf(m3 - mf);
            float den = e0 * pl[row] + e1 * pl[16 + row] + e2 * pl[32 + row] + e3 * pl[48 + row];
            float num = e0 * pO[row * 64 + dh]        + e1 * pO[1024 + row * 64 + dh]
                      + e2 * pO[2048 + row * 64 + dh] + e3 * pO[3072 + row * 64 + dh];
            out[((size_t)(b * 1024 + i0 + row)) * 1024 + h * 64 + dh] = num / den;
        }
        __syncthreads();  // pO reads done before next segment's qe writes
    }
}

// ---------------------------------------------------------------------------
extern "C" void kernel_launch(void* const* d_in, const int* in_sizes, int n_in,
                              void* d_out, int out_size, void* d_ws, size_t ws_size,
                              hipStream_t stream) {
    const float* query = (const float*)d_in[0];
    const float* key   = (const float*)d_in[1];
    const float* value = (const float*)d_in[2];
    const float* Wq    = (const float*)d_in[3];
    const float* bq    = (const float*)d_in[4];
    const float* Wk    = (const float*)d_in[5];
    const float* bk    = (const float*)d_in[6];
    const float* Wv    = (const float*)d_in[7];
    const float* bv    = (const float*)d_in[8];
    const float* rel   = (const float*)d_in[9];
    const float* vrel  = (const float*)d_in[10];
    float* out = (float*)d_out;

    char* w = (char*)d_ws;
    unsigned short* qb   = (unsigned short*)(w);              // 4 MiB  [B,H,S,Dh]
    unsigned short* kb   = (unsigned short*)(w + 4194304);    // 4 MiB  [B,H,S,Dh]
    unsigned short* vtb  = (unsigned short*)(w + 8388608);    // 4 MiB  [B,H,Dh,S]
    unsigned short* erb  = (unsigned short*)(w + 12582912);   // 128 KiB [1024,64]
    unsigned short* ervT = (unsigned short*)(w + 12713984);   // 136 KiB [64,1088]

    prep_tables<<<dim3(528), dim3(256), 0, stream>>>(rel, vrel, erb, ervT);
    proj_gemm_all<<<dim3(16, 8, 3), dim3(256), 0, stream>>>(
        query, key, value, Wq, Wk, Wv, bq, bk, bv, qb, kb, vtb);
    attn_kernel<<<dim3(32, 16, 2), dim3(256), 0, stream>>>(qb, kb, vtb, erb, ervT, out);
}

// Round 8
// 216.976 us; speedup vs baseline: 1.7870x; 1.2022x over previous
//
#include <hip/hip_runtime.h>

typedef __bf16 bf16x8 __attribute__((ext_vector_type(8)));
typedef float f32x4 __attribute__((ext_vector_type(4)));

#define MFMA(a, b, c) __builtin_amdgcn_mfma_f32_16x16x32_bf16((a), (b), (c), 0, 0, 0)

// DPP cross-lane (16-lane row reduce): quad_perm xor1=0xB1, xor2=0x4E, row_ror:4=0x124, row_ror:8=0x128
#define DPPF(x, ctrl) __builtin_bit_cast(float, __builtin_amdgcn_mov_dpp(__builtin_bit_cast(int, (x)), (ctrl), 0xF, 0xF, true))

static __device__ __forceinline__ float rowmax16(float v) {
    v = fmaxf(v, DPPF(v, 0xB1));
    v = fmaxf(v, DPPF(v, 0x4E));
    v = fmaxf(v, DPPF(v, 0x124));
    v = fmaxf(v, DPPF(v, 0x128));
    return v;
}
static __device__ __forceinline__ float rowsum16(float v) {
    v += DPPF(v, 0xB1);
    v += DPPF(v, 0x4E);
    v += DPPF(v, 0x124);
    v += DPPF(v, 0x128);
    return v;
}

static __device__ __forceinline__ unsigned short f2b(float f) {
    // fp32 -> bf16, round-to-nearest-even
    unsigned int u = __builtin_bit_cast(unsigned int, f);
    unsigned int lsb = (u >> 16) & 1u;
    u += 0x7fffu + lsb;
    return (unsigned short)(u >> 16);
}

static __device__ __forceinline__ f32x4 zero4() {
    f32x4 z; z[0] = 0.f; z[1] = 0.f; z[2] = 0.f; z[3] = 0.f; return z;
}

// async global->LDS, 16B per lane; LDS dest = wave-uniform base + lane*16
typedef __attribute__((address_space(3))) unsigned int lds_as_t;
typedef const __attribute__((address_space(1))) unsigned int glb_as_t;
static __device__ __forceinline__ void gload16(const void* g, void* l) {
    __builtin_amdgcn_global_load_lds((glb_as_t*)g, (lds_as_t*)l, 16, 0, 0);
}

// ---------------------------------------------------------------------------
// prep_convert: one BW-bound pass.
//  - q/k/v fp32 [2048][1024] -> bf16 (same layout)          3 x 524288 groups
//  - Wq/Wk/Wv fp32 [1024][1024] -> bf16                     3 x 262144 groups
//  - rel -> erb bf16 [1024][64]                                  16384 groups
//  - vrel -> ervT bf16 [64][1088], ervT[dh][47+r]=vrel[r][dh]    69632 scalars
// ---------------------------------------------------------------------------
__global__ __launch_bounds__(256) void prep_convert(
    const float* __restrict__ q, const float* __restrict__ k, const float* __restrict__ v,
    const float* __restrict__ wq, const float* __restrict__ wk, const float* __restrict__ wv,
    const float* __restrict__ rel, const float* __restrict__ vrel,
    unsigned short* __restrict__ xq, unsigned short* __restrict__ xk, unsigned short* __restrict__ xv,
    unsigned short* __restrict__ wqb, unsigned short* __restrict__ wkb, unsigned short* __restrict__ wvb,
    unsigned short* __restrict__ erb, unsigned short* __restrict__ ervT)
{
    const int NG = 2375680;  // float4 groups total
    for (int g = blockIdx.x * 256 + threadIdx.x; g < NG + 69632; g += gridDim.x * 256) {
        if (g < NG) {
            const float* src; unsigned short* dst; int off;
            if (g < 1572864) {
                int s = g / 524288; off = g - s * 524288;
                src = s == 0 ? q : s == 1 ? k : v;
                dst = s == 0 ? xq : s == 1 ? xk : xv;
            } else if (g < 2359296) {
                int s = (g - 1572864) / 262144; off = g - 1572864 - s * 262144;
                src = s == 0 ? wq : s == 1 ? wk : wv;
                dst = s == 0 ? wqb : s == 1 ? wkb : wvb;
            } else {
                off = g - 2359296; src = rel; dst = erb;
            }
            float4 x = *(const float4*)(src + (size_t)off * 4);
            *(ushort4*)(dst + (size_t)off * 4) =
                make_ushort4(f2b(x.x), f2b(x.y), f2b(x.z), f2b(x.w));
        } else {
            int j = g - NG;
            int dh = j / 1088, c = j % 1088, r = c - 47;
            ervT[j] = (r >= 0 && r < 1024) ? f2b(vrel[r * 64 + dh]) : (unsigned short)0;
        }
    }
}

// ---------------------------------------------------------------------------
// proj_gemm2: fused M=6144 (z = mt>>4 selects q/k/v), N=1024, K=1024, bf16 in.
// BM=128 BN=64 BK=64, 4 waves x 64x32 quadrant, global_load_lds 16B staging
// (no VALU on staging path), 2-barrier loop. 768 blocks (3/CU), bijective
// XCD swizzle (nwg%8==0). z==0 epilogue folds the exact x0.125 score scale
// into Q (power-of-2: bit-exact vs scaling scores later).
// z 0/1: out[((b*16+h)*1024+s)*64+dh] ; z 2: out[((b*16+h)*64+dh)*1024+s].
// ---------------------------------------------------------------------------
__global__ __launch_bounds__(256, 4) void proj_gemm2(
    const unsigned short* __restrict__ xq, const unsigned short* __restrict__ xk,
    const unsigned short* __restrict__ xv,
    const unsigned short* __restrict__ wqb, const unsigned short* __restrict__ wkb,
    const unsigned short* __restrict__ wvb,
    const float* __restrict__ bqp, const float* __restrict__ bkp, const float* __restrict__ bvp,
    unsigned short* __restrict__ oq, unsigned short* __restrict__ ok, unsigned short* __restrict__ ov)
{
    __shared__ unsigned short As[128][64];  // 16 KB, linear (gload_lds needs contiguous dest)
    __shared__ unsigned short Bs[64][64];   //  8 KB

    const int tid = threadIdx.x, lane = tid & 63, w = tid >> 6;
    const int bid = blockIdx.x;                       // 0..767
    const int swz = (bid & 7) * 96 + (bid >> 3);      // bijective XCD swizzle
    const int mt = swz >> 4, nt = swz & 15;           // mt 0..47, nt 0..15
    const int z = mt >> 4;
    const int mm0 = (mt & 15) * 128, n0 = nt * 64;

    const unsigned short* X = z == 0 ? xq : z == 1 ? xk : xv;
    const unsigned short* W = z == 0 ? wqb : z == 1 ? wkb : wvb;
    const float* bias = z == 0 ? bqp : z == 1 ? bkp : bvp;
    unsigned short* outp = z == 0 ? oq : z == 1 ? ok : ov;

    const int wm = (w & 1) * 64, wn = (w >> 1) * 32;
    const int lr = lane & 15, lg = lane >> 4;
    const int arow = lane >> 3, acol = (lane & 7) * 8;  // staging: lane -> (row, col8)

    f32x4 acc[4][2];
#pragma unroll
    for (int a = 0; a < 4; ++a)
#pragma unroll
        for (int bq = 0; bq < 2; ++bq) acc[a][bq] = zero4();

    for (int k0 = 0; k0 < 1024; k0 += 64) {
        // stage A (16 chunks of 1024B; wave w owns w,w+4,w+8,w+12) + B (8 chunks)
#pragma unroll
        for (int c = 0; c < 4; ++c) {
            int ch = w + c * 4;
            gload16(X + (size_t)(mm0 + ch * 8 + arow) * 1024 + k0 + acol, &As[ch * 8][0]);
        }
#pragma unroll
        for (int c = 0; c < 2; ++c) {
            int ch = w + c * 4;
            gload16(W + (size_t)(n0 + ch * 8 + arow) * 1024 + k0 + acol, &Bs[ch * 8][0]);
        }
        __syncthreads();  // compiler drains vmcnt before s_barrier

        bf16x8 af[4][2], bg[2][2];
#pragma unroll
        for (int m4 = 0; m4 < 4; ++m4)
#pragma unroll
            for (int ks = 0; ks < 2; ++ks)
                af[m4][ks] = *(const bf16x8*)&As[wm + m4 * 16 + lr][ks * 32 + lg * 8];
#pragma unroll
        for (int n2 = 0; n2 < 2; ++n2)
#pragma unroll
            for (int ks = 0; ks < 2; ++ks)
                bg[n2][ks] = *(const bf16x8*)&Bs[wn + n2 * 16 + lr][ks * 32 + lg * 8];
#pragma unroll
        for (int m4 = 0; m4 < 4; ++m4)
#pragma unroll
            for (int n2 = 0; n2 < 2; ++n2)
#pragma unroll
                for (int ks = 0; ks < 2; ++ks)
                    acc[m4][n2] = MFMA(af[m4][ks], bg[n2][ks], acc[m4][n2]);
        __syncthreads();  // reads done before next stage overwrites
    }

#pragma unroll
    for (int m4 = 0; m4 < 4; ++m4)
#pragma unroll
        for (int n2 = 0; n2 < 2; ++n2)
#pragma unroll
            for (int r = 0; r < 4; ++r) {
                int mrow = mm0 + wm + m4 * 16 + lg * 4 + r;  // C row = (lane>>4)*4 + reg
                int n = n0 + wn + n2 * 16 + lr;              // C col = lane&15
                float vv = acc[m4][n2][r] + bias[n];
                if (z == 0) vv *= 0.125f;                    // fold score scale into Q (exact)
                int b = mrow >> 10, s = mrow & 1023, h = n >> 6, dh = n & 63;
                unsigned short bv = f2b(vv);
                if (z == 2)
                    outp[(((size_t)(b * 16 + h)) * 64 + dh) * 1024 + s] = bv;
                else
                    outp[(((size_t)(b * 16 + h)) * 1024 + s) * 64 + dh] = bv;
            }
}

// ---------------------------------------------------------------------------
// Fused causal attention with relative-position bias (scores and values).
// Paired q-tiles (qt, 63-qt) per block -> uniform 33 KV-tiles. 4 waves split
// KV tiles, wave-private softmax state + LDS slices (no in-loop barriers).
// ALL 22 per-tile b128 global loads hoisted to the tile top so they issue as
// one pipelined batch (round-7 counters showed VGPR=64 -> serialized loads);
// launch_bounds relaxed to let the compiler hold the payload in registers.
// Q arrives pre-scaled by 0.125 from proj (exact), so no scale here.
// ---------------------------------------------------------------------------
__global__ __launch_bounds__(256) void attn_kernel(
    const unsigned short* __restrict__ qb, const unsigned short* __restrict__ kb,
    const unsigned short* __restrict__ vtb, const unsigned short* __restrict__ erb,
    const unsigned short* __restrict__ ervT, float* __restrict__ out)
{
    const int bx = blockIdx.x, h = blockIdx.y, b = blockIdx.z;
    const int bh = b * 16 + h;
    const int tid = threadIdx.x;
    const int lane = tid & 63, w = tid >> 6;
    const int lr = lane & 15, lg = lane >> 4;

    // Layout: [0,12800) qe (4 x [16][50] f32) | [12800,16896) p (4 x [16][32] u16)
    //         [16896,17408) pm/pl | [17408,25600) prv (4 x [16][64] u16)
    // Combine-phase pO = [0,16384) f32 (after barrier; never touches pm/pl/prv).
    __shared__ __align__(16) char smem[25600];
    float* qe_w = (float*)(smem + w * 3200);                             // [16][50]
    unsigned short* p_w   = (unsigned short*)(smem + 12800 + w * 1024);  // [16][32]
    unsigned short* prv_w = (unsigned short*)(smem + 17408 + w * 2048);  // [16][64]
    float* pO = (float*)smem;              // [4][16][64]
    float* pm = (float*)(smem + 16896);    // [4][16]
    float* pl = pm + 64;                   // [4][16]

    // zero own prv slice once; unwritten slots stay zero forever
    for (int t = lane; t < 16 * 64; t += 64) prv_w[t] = 0;

    for (int seg = 0; seg < 2; ++seg) {
        const int qt = seg == 0 ? bx : 63 - bx;
        const int i0 = qt * 16;

        const unsigned short* qbase = qb + (((size_t)bh * 1024) + i0 + lr) * 64 + lg * 8;
        const bf16x8 qf0 = *(const bf16x8*)qbase;         // dh 0..31 (pre-scaled by 1/8)
        const bf16x8 qf1 = *(const bf16x8*)(qbase + 32);  // dh 32..63

        f32x4 oacc[4];
        float m_run[4], l_run[4];
#pragma unroll
        for (int r = 0; r < 4; ++r) { oacc[r] = zero4(); m_run[r] = -1e30f; l_run[r] = 0.f; }

        const int ntiles = qt / 2 + 1;
        for (int ti = w; ti < ntiles; ti += 4) {
            const int j0 = ti * 32;
            const int dbp = i0 - j0 - 31;  // distance of slot t=0

            // ---- hoisted global loads: 22 x b128, one pipelined batch ----
            bf16x8 kf[2][2], ef[3][2], vf[4], rf[4][2];
#pragma unroll
            for (int ct = 0; ct < 2; ++ct) {
                const unsigned short* kbase =
                    kb + (((size_t)bh * 1024) + j0 + ct * 16 + lr) * 64 + lg * 8;
                kf[ct][0] = *(const bf16x8*)kbase;
                kf[ct][1] = *(const bf16x8*)(kbase + 32);
            }
#pragma unroll
            for (int st = 0; st < 3; ++st) {
                int dr = dbp + st * 16 + lr;
                dr = dr < 0 ? 0 : (dr > 1023 ? 1023 : dr);  // clamped rows feed masked slots only
                const unsigned short* eb = erb + (size_t)dr * 64 + lg * 8;
                ef[st][0] = *(const bf16x8*)eb;
                ef[st][1] = *(const bf16x8*)(eb + 32);
            }
#pragma unroll
            for (int dt = 0; dt < 4; ++dt)
                vf[dt] = *(const bf16x8*)(vtb + ((size_t)bh * 64 + dt * 16 + lr) * 1024 + j0 + lg * 8);
#pragma unroll
            for (int dt = 0; dt < 4; ++dt) {
                const unsigned short* rb2 =
                    ervT + (size_t)(dt * 16 + lr) * 1088 + 47 + dbp + lg * 8;
                rf[dt][0] = *(const bf16x8*)rb2;
                rf[dt][1] = *(const bf16x8*)(rb2 + 32);
            }

            // ---- QK^T ----------------------------------------------------
            f32x4 sacc[2]; sacc[0] = zero4(); sacc[1] = zero4();
#pragma unroll
            for (int ct = 0; ct < 2; ++ct) {
                sacc[ct] = MFMA(qf0, kf[ct][0], sacc[ct]);
                sacc[ct] = MFMA(qf1, kf[ct][1], sacc[ct]);
            }

            // ---- QE: q . er[dbp + t], t in [0,48) ------------------------
            f32x4 qeacc[3];
#pragma unroll
            for (int st = 0; st < 3; ++st) {
                qeacc[st] = zero4();
                qeacc[st] = MFMA(qf0, ef[st][0], qeacc[st]);
                qeacc[st] = MFMA(qf1, ef[st][1], qeacc[st]);
            }

            // ---- scatter qe bias to own LDS ([16][50] f32) ---------------
#pragma unroll
            for (int st = 0; st < 3; ++st)
#pragma unroll
                for (int r = 0; r < 4; ++r)
                    qe_w[(lg * 4 + r) * 50 + st * 16 + lr] = qeacc[st][r];

            // ---- gather bias, mask (scores already carry 1/8 via Q) ------
            float sc2[2][4];
#pragma unroll
            for (int ct = 0; ct < 2; ++ct)
#pragma unroll
                for (int r = 0; r < 4; ++r) {
                    int row  = lg * 4 + r;
                    int jcol = ct * 16 + lr;
                    int t    = row - jcol + 31;             // slot in [0,46]
                    float sc = sacc[ct][r] + qe_w[row * 50 + t];
                    if (j0 + jcol > i0 + row) sc = -1e38f;  // causal mask
                    sc2[ct][r] = sc;
                }

            // ---- online softmax: DPP 16-lane row reduce ------------------
            float p2[2][4];
#pragma unroll
            for (int r = 0; r < 4; ++r) {
                float mx = rowmax16(fmaxf(sc2[0][r], sc2[1][r]));
                float mnew = fmaxf(m_run[r], mx);
                float scale = __expf(m_run[r] - mnew);
                float p0 = __expf(sc2[0][r] - mnew);
                float p1 = __expf(sc2[1][r] - mnew);
                float ps = rowsum16(p0 + p1);
                l_run[r] = l_run[r] * scale + ps;
                m_run[r] = mnew;
#pragma unroll
                for (int dt = 0; dt < 4; ++dt) oacc[dt][r] *= scale;
                p2[0][r] = p0; p2[1][r] = p1;
            }

            // ---- write P (normal + column-reversed) to own LDS slices ----
#pragma unroll
            for (int ct = 0; ct < 2; ++ct)
#pragma unroll
                for (int r = 0; r < 4; ++r) {
                    int row = lg * 4 + r, col = ct * 16 + lr;
                    unsigned short pb = f2b(p2[ct][r]);
                    p_w[row * 32 + col] = pb;
                    prv_w[row * 64 + (row + 31 - col)] = pb;  // slot t in [row, row+31]
                }

            // ---- PV + PR@Erv ---------------------------------------------
            bf16x8 pa   = *(const bf16x8*)&p_w[lr * 32 + lg * 8];
            bf16x8 pra0 = *(const bf16x8*)&prv_w[lr * 64 + lg * 8];       // slots 0..31
            bf16x8 pra1 = *(const bf16x8*)&prv_w[lr * 64 + 32 + lg * 8];  // slots 32..63
#pragma unroll
            for (int dt = 0; dt < 4; ++dt) {
                oacc[dt] = MFMA(pa, vf[dt], oacc[dt]);
                oacc[dt] = MFMA(pra0, rf[dt][0], oacc[dt]);
                oacc[dt] = MFMA(pra1, rf[dt][1], oacc[dt]);
            }
        }

        // ---- merge the 4 wave-partials via LDS --------------------------
        __syncthreads();  // loop-phase LDS reads done before pO overwrites
#pragma unroll
        for (int dt = 0; dt < 4; ++dt)
#pragma unroll
            for (int r = 0; r < 4; ++r)
                pO[w * 1024 + (lg * 4 + r) * 64 + dt * 16 + lr] = oacc[dt][r];
        if (lr == 0)
#pragma unroll
            for (int r = 0; r < 4; ++r) {
                pm[w * 16 + lg * 4 + r] = m_run[r];
                pl[w * 16 + lg * 4 + r] = l_run[r];
            }
        __syncthreads();

        // 16x64 outputs over 256 threads (4 cells each)
#pragma unroll
        for (int k = 0; k < 4; ++k) {
            int c = k * 256 + tid;
            int row = c >> 6, dh = c & 63;
            float m0 = pm[row], m1 = pm[16 + row], m2 = pm[32 + row], m3 = pm[48 + row];
            float mf = fmaxf(fmaxf(m0, m1), fmaxf(m2, m3));
            float e0 = __expf(m0 - mf), e1 = __expf(m1 - mf);
            float e2 = __expf(m2 - mf), e3 = __expf(m3 - mf);
            float den = e0 * pl[row] + e1 * pl[16 + row] + e2 * pl[32 + row] + e3 * pl[48 + row];
            float num = e0 * pO[row * 64 + dh]        + e1 * pO[1024 + row * 64 + dh]
                      + e2 * pO[2048 + row * 64 + dh] + e3 * pO[3072 + row * 64 + dh];
            out[((size_t)(b * 1024 + i0 + row)) * 1024 + h * 64 + dh] = num / den;
        }
        __syncthreads();  // pO reads done before next segment's qe writes
    }
}

// ---------------------------------------------------------------------------
extern "C" void kernel_launch(void* const* d_in, const int* in_sizes, int n_in,
                              void* d_out, int out_size, void* d_ws, size_t ws_size,
                              hipStream_t stream) {
    const float* query = (const float*)d_in[0];
    const float* key   = (const float*)d_in[1];
    const float* value = (const float*)d_in[2];
    const float* Wq    = (const float*)d_in[3];
    const float* bq    = (const float*)d_in[4];
    const float* Wk    = (const float*)d_in[5];
    const float* bk    = (const float*)d_in[6];
    const float* Wv    = (const float*)d_in[7];
    const float* bv    = (const float*)d_in[8];
    const float* rel   = (const float*)d_in[9];
    const float* vrel  = (const float*)d_in[10];
    float* out = (float*)d_out;

    char* w = (char*)d_ws;
    unsigned short* qb   = (unsigned short*)(w);              // 4 MiB  [B,H,S,Dh] (Q pre-scaled 1/8)
    unsigned short* kb   = (unsigned short*)(w + 4194304);    // 4 MiB  [B,H,S,Dh]
    unsigned short* vtb  = (unsigned short*)(w + 8388608);    // 4 MiB  [B,H,Dh,S]
    unsigned short* erb  = (unsigned short*)(w + 12582912);   // 128 KiB [1024,64]
    unsigned short* ervT = (unsigned short*)(w + 12713984);   // 136 KiB [64,1088]
    unsigned short* xq   = (unsigned short*)(w + 12853248);   // 4 MiB bf16 X (query)
    unsigned short* xk   = (unsigned short*)(w + 17047552);   // 4 MiB
    unsigned short* xv   = (unsigned short*)(w + 21241856);   // 4 MiB
    unsigned short* wqb  = (unsigned short*)(w + 25436160);   // 2 MiB bf16 W
    unsigned short* wkb  = (unsigned short*)(w + 27533312);   // 2 MiB
    unsigned short* wvb  = (unsigned short*)(w + 29630464);   // 2 MiB (end ~30.3 MiB)

    prep_convert<<<dim3(2048), dim3(256), 0, stream>>>(
        query, key, value, Wq, Wk, Wv, rel, vrel,
        xq, xk, xv, wqb, wkb, wvb, erb, ervT);
    proj_gemm2<<<dim3(768), dim3(256), 0, stream>>>(
        xq, xk, xv, wqb, wkb, wvb, bq, bk, bv, qb, kb, vtb);
    attn_kernel<<<dim3(32, 16, 2), dim3(256), 0, stream>>>(qb, kb, vtb, erb, ervT, out);
}